// Round 19
// baseline (95.596 us; speedup 1.0000x reference)
//
#include <hip/hip_runtime.h>

#define LN_EPS 1e-5f

static constexpr int Hc  = 512;
static constexpr int Fc  = 16;
static constexpr int Sc  = 1024;
static constexpr int NP  = 8192;   // wave pairs (= blocks); row stride
static constexpr int RPP = 16;     // rows per pair

// ---- prologue: bsum[h] = sum_i b[i][h] (512 floats into d_ws) ----
__global__ void bsum_kernel(const float* __restrict__ b, float* __restrict__ bsum) {
    int h = blockIdx.x * 64 + threadIdx.x;
    float s = 0.f;
#pragma unroll
    for (int i = 0; i < Fc; ++i) s += b[i * Hc + h];
    bsum[h] = s;
}

// ---- DPP wave64 sum ----
template <int CTRL, int RMASK>
__device__ __forceinline__ float dpp_add(float v) {
    int t = __builtin_amdgcn_update_dpp(0, __float_as_int(v), CTRL, RMASK, 0xf, true);
    return v + __int_as_float(t);
}
__device__ __forceinline__ float wave_sum64(float v) {
    v = dpp_add<0x111, 0xf>(v);
    v = dpp_add<0x112, 0xf>(v);
    v = dpp_add<0x114, 0xf>(v);
    v = dpp_add<0x118, 0xf>(v);
    v = dpp_add<0x142, 0xa>(v);
    v = dpp_add<0x143, 0xc>(v);
    return __int_as_float(__builtin_amdgcn_readlane(__float_as_int(v), 63));
}
__device__ __forceinline__ float rdlane(float v, int l) {
    return __int_as_float(__builtin_amdgcn_readlane(__float_as_int(v), l));
}

// bf16 RNE pack helpers (R12-validated): lo = exact bf16 (1 shift);
// hi = raw reg (bf16 + <=2^-8 rel noise from low bits) -- free.
__device__ __forceinline__ unsigned rne16(float f) {
    unsigned u = __float_as_uint(f);
    return (u + 0x7fffu + ((u >> 16) & 1u)) >> 16;
}
__device__ __forceinline__ unsigned pack2(float lo, float hi) {
    return rne16(lo) | (rne16(hi) << 16);
}
__device__ __forceinline__ float lo_f(unsigned p) { return __uint_as_float(p << 16); }
__device__ __forceinline__ float hi_f(unsigned p) { return __uint_as_float(p); }

// ---- fused: wave PAIR per block; each wave 256 cols (4 cols/lane) ----
// Target <=64 VGPR -> 8 waves/SIMD (32 waves/CU): the store-issue wave
// density is the one monotone lever left (2w: 71-77us tier, 4w: 61.5-70us
// tier; all in-tier compute restructures were noise). Register diet:
// W bf16-packed 32, a-values bf16-packed across the exchange 8, ebs/g/be
// packed 6, xq 4 -> ~60. LB(128,4) caps at 64 (cap = 256/min_waves).
// LN exchange batched per 4 rows (R10's per-row barrier regressed; this
// amortizes it 4x), parity double-buffer, lgkmcnt-only waits.
// Dense write band (R17) + burst stores (R18) kept.
__global__ __launch_bounds__(128, 4) void fused_kernel(
    const float* __restrict__ x, const float* __restrict__ W,
    const float* __restrict__ emb, const float* __restrict__ bsum,
    const float* __restrict__ gamma, const float* __restrict__ beta,
    float* __restrict__ out)
{
    __shared__ float2 part[2][2][4];   // [parity][wave][row-in-batch]

    const int lane = threadIdx.x & 63;
    const int wv   = threadIdx.x >> 6;        // 0..1
    const int P    = blockIdx.x;              // pair id 0..8191
    const int s    = P & (Sc - 1);            // NP % Sc == 0 -> s loop-invariant
    const int h    = wv * 256 + lane * 4;

    // packed W panel: 16 K-rows x 4 cols per lane in 32 u32
    unsigned p0[Fc], p1[Fc];
#pragma unroll
    for (int i = 0; i < Fc; ++i) {
        const float4 w4 = *reinterpret_cast<const float4*>(&W[i * Hc + h]);
        p0[i] = pack2(w4.x, w4.y);
        p1[i] = pack2(w4.z, w4.w);
    }

    // x for all 16 rows up front: rows r = k*NP + P, k = q*4 + sub
    const int sub = lane >> 4, i16 = lane & 15;
    float xq[4];
#pragma unroll
    for (int q = 0; q < 4; ++q)
        xq[q] = __builtin_nontemporal_load(
            &x[((size_t)(q * 4 + sub) * NP + P) * Fc + i16]);

    // loop-invariant packed vectors: ebs = emb[s] + bsum; gamma, beta
    unsigned eb01, eb23, gp01, gp23, bp01, bp23;
    {
        const float4 e  = *reinterpret_cast<const float4*>(&emb[(size_t)s * Hc + h]);
        const float4 bs = *reinterpret_cast<const float4*>(&bsum[h]);
        eb01 = pack2(e.x + bs.x, e.y + bs.y);
        eb23 = pack2(e.z + bs.z, e.w + bs.w);
        const float4 g  = *reinterpret_cast<const float4*>(&gamma[h]);
        const float4 be = *reinterpret_cast<const float4*>(&beta[h]);
        gp01 = pack2(g.x, g.y);  gp23 = pack2(g.z, g.w);
        bp01 = pack2(be.x, be.y); bp23 = pack2(be.z, be.w);
    }

#pragma unroll
    for (int m = 0; m < 4; ++m) {           // 4 batches of 4 rows
        unsigned r01[4], r23[4];            // a-values packed bf16 (8 regs)

        // ---- compute phase: 4 rows, stats to LDS ----
#pragma unroll
        for (int u = 0; u < 4; ++u) {
            float ax = lo_f(eb01), ay = hi_f(eb01);
            float az = lo_f(eb23), aw = hi_f(eb23);
#pragma unroll
            for (int i = 0; i < Fc; ++i) {
                const float xi = rdlane(xq[m], u * 16 + i);  // compile-time lane
                ax = fmaf(xi, lo_f(p0[i]), ax);
                ay = fmaf(xi, hi_f(p0[i]), ay);
                az = fmaf(xi, lo_f(p1[i]), az);
                aw = fmaf(xi, hi_f(p1[i]), aw);
            }
            float psum = ax + ay + az + aw;
            float pssq = fmaf(ax, ax, fmaf(ay, ay, fmaf(az, az, aw * aw)));
            const float sum = wave_sum64(psum);
            const float ssq = wave_sum64(pssq);
            if (lane == 0) part[m & 1][wv][u] = make_float2(sum, ssq);
            r01[u] = pack2(ax, ay);
            r23[u] = pack2(az, aw);
        }

        asm volatile("s_waitcnt lgkmcnt(0)" ::: "memory");
        __builtin_amdgcn_s_barrier();
        asm volatile("" ::: "memory");

        // ---- epilogue + burst stores: 4 rows ----
#pragma unroll
        for (int u = 0; u < 4; ++u) {
            const float2 A = part[m & 1][0][u];
            const float2 B = part[m & 1][1][u];
            const float sum = A.x + B.x;
            const float ssq = A.y + B.y;
            const float mean = sum * (1.0f / 512.0f);
            const float var  = ssq * (1.0f / 512.0f) - mean * mean;
            const float rs   = rsqrtf(var + LN_EPS);
            const float nmrs = -mean * rs;

            float4 r;
            r.x = fmaf(fmaf(lo_f(r01[u]), rs, nmrs), lo_f(gp01), lo_f(bp01));
            r.y = fmaf(fmaf(hi_f(r01[u]), rs, nmrs), hi_f(gp01), hi_f(bp01));
            r.z = fmaf(fmaf(lo_f(r23[u]), rs, nmrs), lo_f(gp23), lo_f(bp23));
            r.w = fmaf(fmaf(hi_f(r23[u]), rs, nmrs), hi_f(gp23), hi_f(bp23));

            float* orow = out + ((size_t)(m * 4 + u) * NP + P) * Hc;
            *reinterpret_cast<float4*>(&orow[h]) = r;
        }
    }
}

extern "C" void kernel_launch(void* const* d_in, const int* in_sizes, int n_in,
                              void* d_out, int out_size, void* d_ws, size_t ws_size,
                              hipStream_t stream) {
    const float* x     = (const float*)d_in[0];
    const float* W     = (const float*)d_in[1];
    const float* b     = (const float*)d_in[2];
    const float* emb   = (const float*)d_in[3];
    const float* gamma = (const float*)d_in[4];
    const float* beta  = (const float*)d_in[5];
    float* out  = (float*)d_out;
    float* bsum = (float*)d_ws;     // 512 floats

    bsum_kernel<<<Hc / 64, 64, 0, stream>>>(b, bsum);

    fused_kernel<<<NP, 128, 0, stream>>>(x, W, emb, bsum, gamma, beta, out);
}

// Round 20
// 65.241 us; speedup vs baseline: 1.4653x; 1.4653x over previous
//
#include <hip/hip_runtime.h>

#define LN_EPS 1e-5f

typedef float f32x4 __attribute__((ext_vector_type(4)));

static constexpr int Hc  = 512;
static constexpr int Fc  = 16;
static constexpr int Sc  = 1024;
static constexpr int NW  = 4096;     // total waves; row stride for grid-stride

// ---- DPP wave64 sum: 6 VALU steps + readlane, no LDS, no barriers ----
template <int CTRL, int RMASK>
__device__ __forceinline__ float dpp_add(float v) {
    int t = __builtin_amdgcn_update_dpp(0, __float_as_int(v), CTRL, RMASK, 0xf, true);
    return v + __int_as_float(t);
}
__device__ __forceinline__ float wave_sum64(float v) {
    v = dpp_add<0x111, 0xf>(v);   // row_shr:1
    v = dpp_add<0x112, 0xf>(v);   // row_shr:2
    v = dpp_add<0x114, 0xf>(v);   // row_shr:4
    v = dpp_add<0x118, 0xf>(v);   // row_shr:8
    v = dpp_add<0x142, 0xa>(v);   // row_bcast:15
    v = dpp_add<0x143, 0xc>(v);   // row_bcast:31 -> lane63 has total
    return __int_as_float(__builtin_amdgcn_readlane(__float_as_int(v), 63));
}
__device__ __forceinline__ float rdlane(float v, int l) {
    return __int_as_float(__builtin_amdgcn_readlane(__float_as_int(v), l));
}

// bf16 RNE round; pack two cols per u32.
__device__ __forceinline__ unsigned rne16(float f) {
    unsigned u = __float_as_uint(f);
    return (u + 0x7fffu + ((u >> 16) & 1u)) >> 16;
}
__device__ __forceinline__ unsigned pack2(float lo, float hi) {
    return rne16(lo) | (rne16(hi) << 16);
}
__device__ __forceinline__ float lo_f(unsigned p) { return __uint_as_float(p << 16); }
__device__ __forceinline__ float hi_f(unsigned p) { return __uint_as_float(p); }

__device__ __forceinline__ void nt_store4(float* p, const float4& v) {
    f32x4 t; t.x = v.x; t.y = v.y; t.z = v.z; t.w = v.w;
    __builtin_nontemporal_store(t, reinterpret_cast<f32x4*>(p));
}

// ---- fused: wave w handles rows r = w + k*NW; dense write band + bursts ----
// R20 = R18 (dense band, 4-row burst stores, bf16-packed W, zero in-loop
// VMEM) with NONTEMPORAL burst stores: R8's NT-vs-plain A/B was run on the
// SCATTERED pattern (both random drain order -> NT couldn't matter). On the
// dense band, NT bypasses L2 -> the write stream hits HBM as a pure
// sequential train (memset-like), skipping dirty-line writeback latency.
// Also: bsum folded into the wave prologue (one dispatch instead of two).
// LB(256,2): cap 128 VGPR -> 4 waves/SIMD; R18 showed no spill signature.
__global__ __launch_bounds__(256, 2) void fused_kernel(
    const float* __restrict__ x, const float* __restrict__ W,
    const float* __restrict__ b, const float* __restrict__ emb,
    const float* __restrict__ gamma, const float* __restrict__ beta,
    float* __restrict__ out)
{
    const int lane = threadIdx.x & 63;
    const int w    = (blockIdx.x << 2) | (threadIdx.x >> 6);   // 0..4095
    const int s    = w & (Sc - 1);
    const int h0 = lane * 4, h1 = h0 + 256;

    // packed W panel: 16 K-rows x 8 cols per lane in 64 u32
    unsigned p00[Fc], p01[Fc], p10[Fc], p11[Fc];
#pragma unroll
    for (int i = 0; i < Fc; ++i) {
        const float4 wa = *reinterpret_cast<const float4*>(&W[i * Hc + h0]);
        const float4 wb = *reinterpret_cast<const float4*>(&W[i * Hc + h1]);
        p00[i] = pack2(wa.x, wa.y);
        p01[i] = pack2(wa.z, wa.w);
        p10[i] = pack2(wb.x, wb.y);
        p11[i] = pack2(wb.z, wb.w);
    }

    // x for all 32 rows up front: 8 gather loads; xq[q] lane l holds
    // x[r = (q*4 + (l>>4))*NW + w][l&15]
    const int sub = lane >> 4, i16 = lane & 15;
    float xq[8];
#pragma unroll
    for (int q = 0; q < 8; ++q)
        xq[q] = __builtin_nontemporal_load(
            &x[((size_t)(q * 4 + sub) * NW + w) * Fc + i16]);

    // ebs = emb[s] + sum_i b[i]  (bsum folded; b rows are L2-resident)
    float4 ebs0 = *reinterpret_cast<const float4*>(&emb[(size_t)s * Hc + h0]);
    float4 ebs1 = *reinterpret_cast<const float4*>(&emb[(size_t)s * Hc + h1]);
#pragma unroll
    for (int i = 0; i < Fc; ++i) {
        const float4 ba = *reinterpret_cast<const float4*>(&b[i * Hc + h0]);
        const float4 bb = *reinterpret_cast<const float4*>(&b[i * Hc + h1]);
        ebs0.x += ba.x; ebs0.y += ba.y; ebs0.z += ba.z; ebs0.w += ba.w;
        ebs1.x += bb.x; ebs1.y += bb.y; ebs1.z += bb.z; ebs1.w += bb.w;
    }

    const float4 g0  = *reinterpret_cast<const float4*>(&gamma[h0]);
    const float4 g1  = *reinterpret_cast<const float4*>(&gamma[h1]);
    const float4 be0 = *reinterpret_cast<const float4*>(&beta[h0]);
    const float4 be1 = *reinterpret_cast<const float4*>(&beta[h1]);

#pragma unroll 1
    for (int q = 0; q < 8; ++q) {
        float4 res0[4], res1[4];   // distinct regs per row (u unrolled)

        // ---- compute phase: 4 rows, no stores ----
#pragma unroll
        for (int u = 0; u < 4; ++u) {
            float4 a0 = ebs0, a1 = ebs1;
#pragma unroll
            for (int i = 0; i < Fc; ++i) {
                const float xi = rdlane(xq[0], u * 16 + i);   // compile-time lane
                a0.x = fmaf(xi, lo_f(p00[i]), a0.x);
                a0.y = fmaf(xi, hi_f(p00[i]), a0.y);
                a0.z = fmaf(xi, lo_f(p01[i]), a0.z);
                a0.w = fmaf(xi, hi_f(p01[i]), a0.w);
                a1.x = fmaf(xi, lo_f(p10[i]), a1.x);
                a1.y = fmaf(xi, hi_f(p10[i]), a1.y);
                a1.z = fmaf(xi, lo_f(p11[i]), a1.z);
                a1.w = fmaf(xi, hi_f(p11[i]), a1.w);
            }

            float psum = a0.x + a0.y + a0.z + a0.w + a1.x + a1.y + a1.z + a1.w;
            float pssq = fmaf(a0.x, a0.x, fmaf(a0.y, a0.y, fmaf(a0.z, a0.z, a0.w * a0.w)));
            pssq = fmaf(a1.x, a1.x, fmaf(a1.y, a1.y, fmaf(a1.z, a1.z, fmaf(a1.w, a1.w, pssq))));

            const float sum = wave_sum64(psum);
            const float ssq = wave_sum64(pssq);

            const float mean = sum * (1.0f / 512.0f);
            const float var  = ssq * (1.0f / 512.0f) - mean * mean;
            const float rs   = rsqrtf(var + LN_EPS);
            const float nmrs = -mean * rs;

            res0[u].x = fmaf(fmaf(a0.x, rs, nmrs), g0.x, be0.x);
            res0[u].y = fmaf(fmaf(a0.y, rs, nmrs), g0.y, be0.y);
            res0[u].z = fmaf(fmaf(a0.z, rs, nmrs), g0.z, be0.z);
            res0[u].w = fmaf(fmaf(a0.w, rs, nmrs), g0.w, be0.w);
            res1[u].x = fmaf(fmaf(a1.x, rs, nmrs), g1.x, be1.x);
            res1[u].y = fmaf(fmaf(a1.y, rs, nmrs), g1.y, be1.y);
            res1[u].z = fmaf(fmaf(a1.z, rs, nmrs), g1.z, be1.z);
            res1[u].w = fmaf(fmaf(a1.w, rs, nmrs), g1.w, be1.w);
        }

        // ---- burst phase: 8 NT stores back-to-back (L2 bypass) ----
#pragma unroll
        for (int u = 0; u < 4; ++u) {
            float* orow = out + ((size_t)(q * 4 + u) * NW + w) * Hc;
            nt_store4(&orow[h0], res0[u]);
            nt_store4(&orow[h1], res1[u]);
        }

        // shift-register rotation: next q consumes xq[0]
#pragma unroll
        for (int j = 0; j < 7; ++j) xq[j] = xq[j + 1];
    }
}

extern "C" void kernel_launch(void* const* d_in, const int* in_sizes, int n_in,
                              void* d_out, int out_size, void* d_ws, size_t ws_size,
                              hipStream_t stream) {
    const float* x     = (const float*)d_in[0];
    const float* W     = (const float*)d_in[1];
    const float* b     = (const float*)d_in[2];
    const float* emb   = (const float*)d_in[3];
    const float* gamma = (const float*)d_in[4];
    const float* beta  = (const float*)d_in[5];
    float* out = (float*)d_out;

    const int blocks = NW / 4;   // 1024 blocks x 4 waves
    fused_kernel<<<blocks, 256, 0, stream>>>(x, W, b, emb, gamma, beta, out);
}

// Round 21
// 60.224 us; speedup vs baseline: 1.5873x; 1.0833x over previous
//
#include <hip/hip_runtime.h>

#define LN_EPS 1e-5f

static constexpr int Hc  = 512;
static constexpr int Fc  = 16;
static constexpr int Sc  = 1024;
static constexpr int NW  = 4096;     // total waves; row stride for grid-stride

// ---- prologue: bsum[h] = sum_i b[i][h] (512 floats into d_ws) ----
__global__ void bsum_kernel(const float* __restrict__ b, float* __restrict__ bsum) {
    int h = blockIdx.x * 64 + threadIdx.x;
    float s = 0.f;
#pragma unroll
    for (int i = 0; i < Fc; ++i) s += b[i * Hc + h];
    bsum[h] = s;
}

// ---- DPP wave64 sum: 6 VALU steps + readlane, no LDS, no barriers ----
template <int CTRL, int RMASK>
__device__ __forceinline__ float dpp_add(float v) {
    int t = __builtin_amdgcn_update_dpp(0, __float_as_int(v), CTRL, RMASK, 0xf, true);
    return v + __int_as_float(t);
}
__device__ __forceinline__ float wave_sum64(float v) {
    v = dpp_add<0x111, 0xf>(v);
    v = dpp_add<0x112, 0xf>(v);
    v = dpp_add<0x114, 0xf>(v);
    v = dpp_add<0x118, 0xf>(v);
    v = dpp_add<0x142, 0xa>(v);
    v = dpp_add<0x143, 0xc>(v);
    return __int_as_float(__builtin_amdgcn_readlane(__float_as_int(v), 63));
}
__device__ __forceinline__ float rdlane(float v, int l) {
    return __int_as_float(__builtin_amdgcn_readlane(__float_as_int(v), l));
}

// bf16 RNE round; pack two cols per u32.
__device__ __forceinline__ unsigned rne16(float f) {
    unsigned u = __float_as_uint(f);
    return (u + 0x7fffu + ((u >> 16) & 1u)) >> 16;
}
__device__ __forceinline__ unsigned pack2(float lo, float hi) {
    return rne16(lo) | (rne16(hi) << 16);
}
__device__ __forceinline__ float lo_f(unsigned p) { return __uint_as_float(p << 16); }
__device__ __forceinline__ float hi_f(unsigned p) { return __uint_as_float(p); }

// ---- fused: wave w handles rows r = w + k*NW; dense band + DOUBLE-BUFFERED
// burst stores. R18's single res buffer serializes compute and drain: the
// wave rewrites res next q-iter -> WAR -> vmcnt wait for its OWN previous
// burst's completion (measured period 18.5k cyc = 12.5k drain + 4.4k compute,
// matching the queueing model exactly). Alternating A/B buffers moves the
// WAR wait 2 bursts back -> burst q in flight through all of q+1's compute ->
// period = max(compute, drain) = drain ~ 6.3 TB/s, occupancy-tier independent.
// Buffer choice is compile-time: two inlined bodies per qq-iter; xq shift-
// register by 2 (no runtime-indexed arrays -> no scratch).
// Natural VGPR (~170, 2-3 waves/SIMD): NO min-waves cap (R4/R11 spills).
__global__ __launch_bounds__(256) void fused_kernel(
    const float* __restrict__ x, const float* __restrict__ W,
    const float* __restrict__ emb, const float* __restrict__ bsum,
    const float* __restrict__ gamma, const float* __restrict__ beta,
    float* __restrict__ out)
{
    const int lane = threadIdx.x & 63;
    const int w    = (blockIdx.x << 2) | (threadIdx.x >> 6);   // 0..4095
    const int s    = w & (Sc - 1);
    const int h0 = lane * 4, h1 = h0 + 256;

    // packed W panel: 16 K-rows x 8 cols per lane in 64 u32
    unsigned p00[Fc], p01[Fc], p10[Fc], p11[Fc];
#pragma unroll
    for (int i = 0; i < Fc; ++i) {
        const float4 wa = *reinterpret_cast<const float4*>(&W[i * Hc + h0]);
        const float4 wb = *reinterpret_cast<const float4*>(&W[i * Hc + h1]);
        p00[i] = pack2(wa.x, wa.y);
        p01[i] = pack2(wa.z, wa.w);
        p10[i] = pack2(wb.x, wb.y);
        p11[i] = pack2(wb.z, wb.w);
    }

    // x for all 32 rows up front
    const int sub = lane >> 4, i16 = lane & 15;
    float xq[8];
#pragma unroll
    for (int q = 0; q < 8; ++q)
        xq[q] = __builtin_nontemporal_load(
            &x[((size_t)(q * 4 + sub) * NW + w) * Fc + i16]);

    // loop-invariant per-wave vectors
    const float4 g0  = *reinterpret_cast<const float4*>(&gamma[h0]);
    const float4 g1  = *reinterpret_cast<const float4*>(&gamma[h1]);
    const float4 be0 = *reinterpret_cast<const float4*>(&beta[h0]);
    const float4 be1 = *reinterpret_cast<const float4*>(&beta[h1]);
    float4 ebs0, ebs1;
    {
        const float4 e0  = *reinterpret_cast<const float4*>(&emb[(size_t)s * Hc + h0]);
        const float4 e1  = *reinterpret_cast<const float4*>(&emb[(size_t)s * Hc + h1]);
        const float4 bs0 = *reinterpret_cast<const float4*>(&bsum[h0]);
        const float4 bs1 = *reinterpret_cast<const float4*>(&bsum[h1]);
        ebs0.x = e0.x + bs0.x; ebs0.y = e0.y + bs0.y; ebs0.z = e0.z + bs0.z; ebs0.w = e0.w + bs0.w;
        ebs1.x = e1.x + bs1.x; ebs1.y = e1.y + bs1.y; ebs1.z = e1.z + bs1.z; ebs1.w = e1.w + bs1.w;
    }

    float4 rA0[4], rA1[4], rB0[4], rB1[4];   // double-buffered burst regs

    // one 4-row batch: compute into res, then burst-store 8
    auto BATCH = [&](int q, const float xsrc, float4* res0, float4* res1) {
#pragma unroll
        for (int u = 0; u < 4; ++u) {
            float4 a0 = ebs0, a1 = ebs1;
#pragma unroll
            for (int i = 0; i < Fc; ++i) {
                const float xi = rdlane(xsrc, u * 16 + i);   // compile-time lane
                a0.x = fmaf(xi, lo_f(p00[i]), a0.x);
                a0.y = fmaf(xi, hi_f(p00[i]), a0.y);
                a0.z = fmaf(xi, lo_f(p01[i]), a0.z);
                a0.w = fmaf(xi, hi_f(p01[i]), a0.w);
                a1.x = fmaf(xi, lo_f(p10[i]), a1.x);
                a1.y = fmaf(xi, hi_f(p10[i]), a1.y);
                a1.z = fmaf(xi, lo_f(p11[i]), a1.z);
                a1.w = fmaf(xi, hi_f(p11[i]), a1.w);
            }

            float psum = a0.x + a0.y + a0.z + a0.w + a1.x + a1.y + a1.z + a1.w;
            float pssq = fmaf(a0.x, a0.x, fmaf(a0.y, a0.y, fmaf(a0.z, a0.z, a0.w * a0.w)));
            pssq = fmaf(a1.x, a1.x, fmaf(a1.y, a1.y, fmaf(a1.z, a1.z, fmaf(a1.w, a1.w, pssq))));

            const float sum = wave_sum64(psum);
            const float ssq = wave_sum64(pssq);

            const float mean = sum * (1.0f / 512.0f);
            const float var  = ssq * (1.0f / 512.0f) - mean * mean;
            const float rs   = rsqrtf(var + LN_EPS);
            const float nmrs = -mean * rs;

            res0[u].x = fmaf(fmaf(a0.x, rs, nmrs), g0.x, be0.x);
            res0[u].y = fmaf(fmaf(a0.y, rs, nmrs), g0.y, be0.y);
            res0[u].z = fmaf(fmaf(a0.z, rs, nmrs), g0.z, be0.z);
            res0[u].w = fmaf(fmaf(a0.w, rs, nmrs), g0.w, be0.w);
            res1[u].x = fmaf(fmaf(a1.x, rs, nmrs), g1.x, be1.x);
            res1[u].y = fmaf(fmaf(a1.y, rs, nmrs), g1.y, be1.y);
            res1[u].z = fmaf(fmaf(a1.z, rs, nmrs), g1.z, be1.z);
            res1[u].w = fmaf(fmaf(a1.w, rs, nmrs), g1.w, be1.w);
        }
#pragma unroll
        for (int u = 0; u < 4; ++u) {
            float* orow = out + ((size_t)(q * 4 + u) * NW + w) * Hc;
            *reinterpret_cast<float4*>(&orow[h0]) = res0[u];
            *reinterpret_cast<float4*>(&orow[h1]) = res1[u];
        }
    };

#pragma unroll 1
    for (int qq = 0; qq < 4; ++qq) {
        BATCH(2 * qq,     xq[0], rA0, rA1);   // buffer A
        BATCH(2 * qq + 1, xq[1], rB0, rB1);   // buffer B (A's stores in flight)
        // shift-register: next qq consumes xq[0], xq[1]
#pragma unroll
        for (int j = 0; j < 6; ++j) xq[j] = xq[j + 2];
    }
}

extern "C" void kernel_launch(void* const* d_in, const int* in_sizes, int n_in,
                              void* d_out, int out_size, void* d_ws, size_t ws_size,
                              hipStream_t stream) {
    const float* x     = (const float*)d_in[0];
    const float* W     = (const float*)d_in[1];
    const float* b     = (const float*)d_in[2];
    const float* emb   = (const float*)d_in[3];
    const float* gamma = (const float*)d_in[4];
    const float* beta  = (const float*)d_in[5];
    float* out  = (float*)d_out;
    float* bsum = (float*)d_ws;     // 512 floats

    bsum_kernel<<<Hc / 64, 64, 0, stream>>>(b, bsum);

    const int blocks = NW / 4;   // 1024 blocks x 4 waves
    fused_kernel<<<blocks, 256, 0, stream>>>(x, W, emb, bsum, gamma, beta, out);
}